// Round 3
// baseline (478.647 us; speedup 1.0000x reference)
//
#include <hip/hip_runtime.h>
#include <hip/hip_bf16.h>
#include <math.h>

#define B_ 64
#define T_ 4096
#define C_ 256
#define H_ 4
#define HD_ 64
#define EPS_ 1e-5f

typedef __attribute__((ext_vector_type(4))) float floatx4;
typedef __attribute__((ext_vector_type(8))) short short8;   // 8 bf16 = 4 VGPRs (MFMA A/B frag)

#if __has_builtin(__builtin_amdgcn_cvt_pk_bf16_f32)
typedef __attribute__((ext_vector_type(2))) __bf16 bf16x2_t;
__device__ __forceinline__ unsigned int pack_bf16x2(float a, float b) {
    bf16x2_t v = __builtin_amdgcn_cvt_pk_bf16_f32(a, b);
    return __builtin_bit_cast(unsigned int, v);
}
#else
__device__ __forceinline__ unsigned int pack_bf16x2(float a, float b) {
    unsigned int ua = __builtin_bit_cast(unsigned int, a);
    unsigned int ub = __builtin_bit_cast(unsigned int, b);
    ua = (ua + 0x7fffu + ((ua >> 16) & 1u)) >> 16;   // RNE
    ub = (ub + 0x7fffu + ((ub >> 16) & 1u)) >> 16;
    return ua | (ub << 16);
}
#endif

// tanh(x) = sign(x) * (1 - e) * rcp(1 + e), e = exp(-2|x|)
__device__ __forceinline__ float fast_tanh(float v) {
    float a = fabsf(v);
    float e = __expf(-2.0f * a);
#if __has_builtin(__builtin_amdgcn_rcpf)
    float r = (1.0f - e) * __builtin_amdgcn_rcpf(1.0f + e);
#else
    float r = (1.0f - e) / (1.0f + e);
#endif
    return copysignf(r, v);
}

// ---------------- K0: W1 (H,C,HD) fp32 -> fragment-major bf16 B-operand ----------------
// w1f[((h*8 + ks)*4 + nb)*64 + lane] = uint4 holding 8 bf16:
//   B[nb*16 + nl][ks*32 + q*8 + j], j=0..7   (nl = lane&15, q = lane>>4)
// so the k1 K-loop B-load is ONE fully-coalesced 16B/lane (1 KiB/wave) transaction.
__global__ void k0_w1frag(const float* __restrict__ W1, uint4* __restrict__ w1f) {
    int h  = blockIdx.x >> 3;       // grid 32 = H*8
    int ks = blockIdx.x & 7;
    int nb = threadIdx.x >> 6;      // 4 waves = 4 n-tiles
    int l  = threadIdx.x & 63;
    int nl = l & 15, q = l >> 4;
    int d  = nb * 16 + nl;
    const float* src = W1 + ((long)h * C_ + ks * 32 + q * 8) * HD_ + d;
    float v[8];
    #pragma unroll
    for (int j = 0; j < 8; ++j) v[j] = src[j * HD_];
    uint4 ua;
    ua.x = pack_bf16x2(v[0], v[1]); ua.y = pack_bf16x2(v[2], v[3]);
    ua.z = pack_bf16x2(v[4], v[5]); ua.w = pack_bf16x2(v[6], v[7]);
    w1f[((long)blockIdx.x * 4 + nb) * 64 + l] = ua;
}

// ---------------- K1 fused: scores (MFMA) + partial softmax + partial context ----------------
// grid 4096 (64 rows each), block 512 = 8 waves; wave wid = (head h = wid>>1, n-half nh = wid&1).
// Each wave: full 64 rows x 32 d-cols of its head (acc 4x2), 16 coalesced B-loads.
// 8 waves share ONE 33 KiB A-tile -> 4 blocks/CU * 8 waves = 32 waves/CU (100% occupancy).
// d-partial scores summed across sibling waves via LDS in phase 2.
#define ASTRIDE 264   // bf16 elements per row (256 + 8 pad); 132 dwords, %32==4 -> 2-way only
__global__ __launch_bounds__(512, 4)
void k1_fused(const float* __restrict__ x, const uint4* __restrict__ w1f,
              const float* __restrict__ b1, const float* __restrict__ w2,
              float* __restrict__ rawscore, float* __restrict__ ctxp,
              float* __restrict__ mS) {
    __shared__ __align__(16) unsigned short shA[64 * ASTRIDE];  // 33 KiB, whole A tile
    __shared__ float sS[2 * 4 * 64];               // [nh][h][t] d-partial raw scores
    __shared__ __align__(16) float sP4[64 * 4];    // exp(s - m_loc), layout [t][h]

    const int tid  = threadIdx.x;
    const int lane = tid & 63;
    const int wid  = tid >> 6;        // 0..7
    const int h    = wid >> 1;        // head
    const int nh   = wid & 1;         // n-half: nb in {2nh, 2nh+1}
    const int nl   = lane & 15;
    const int q    = lane >> 4;
    const int rowbase = blockIdx.x * 64;       // row = b*T + t
    const int b       = blockIdx.x >> 6;       // 64 blocks per batch
    const int tbase   = (blockIdx.x & 63) * 64;

    // ---- stage full A tile: thread -> row tid>>3, 32 contiguous cols ----
    {
        const int arow = tid >> 3;          // 0..63
        const int acol = (tid & 7) * 32;    // 0..224
        const float4* ap = (const float4*)(x + (long)(rowbase + arow) * C_ + acol);
        #pragma unroll
        for (int i = 0; i < 4; ++i) {
            float4 f0 = ap[2 * i], f1 = ap[2 * i + 1];
            uint4 ua;
            ua.x = pack_bf16x2(f0.x, f0.y); ua.y = pack_bf16x2(f0.z, f0.w);
            ua.z = pack_bf16x2(f1.x, f1.y); ua.w = pack_bf16x2(f1.z, f1.w);
            *(uint4*)&shA[arow * ASTRIDE + acol + i * 8] = ua;
        }
    }

    floatx4 acc[4][2];
    #pragma unroll
    for (int i = 0; i < 4; ++i)
        #pragma unroll
        for (int j = 0; j < 2; ++j)
            acc[i][j] = (floatx4){0.f, 0.f, 0.f, 0.f};

    // per-head fragment base; this wave's nb = 2*nh + nb2
    const uint4* bW = w1f + (long)h * (8 * 4 * 64) + lane;

    // prefetch ks=0 B-fragments BEFORE the barrier (independent of LDS)
    uint4 bFa[2], bFb[2];
    #pragma unroll
    for (int nb2 = 0; nb2 < 2; ++nb2) bFa[nb2] = bW[(nh * 2 + nb2) * 64];

    __syncthreads();   // the ONLY K-side barrier

    // ---- K-loop: 8 steps x 8 MFMA/wave, depth-1 B prefetch, all indices static ----
    #pragma unroll
    for (int kp = 0; kp < 4; ++kp) {
        const int ks0 = 2 * kp, ks1 = 2 * kp + 1;
        #pragma unroll
        for (int nb2 = 0; nb2 < 2; ++nb2) bFb[nb2] = bW[(ks1 * 4 + nh * 2 + nb2) * 64];
        #pragma unroll
        for (int mb = 0; mb < 4; ++mb) {
            short8 a = *(const short8*)&shA[(mb * 16 + nl) * ASTRIDE + ks0 * 32 + q * 8];
            #pragma unroll
            for (int nb2 = 0; nb2 < 2; ++nb2)
                acc[mb][nb2] = __builtin_amdgcn_mfma_f32_16x16x32_bf16(
                    a, __builtin_bit_cast(short8, bFa[nb2]), acc[mb][nb2], 0, 0, 0);
        }
        if (kp < 3) {
            #pragma unroll
            for (int nb2 = 0; nb2 < 2; ++nb2) bFa[nb2] = bW[((ks0 + 2) * 4 + nh * 2 + nb2) * 64];
        }
        #pragma unroll
        for (int mb = 0; mb < 4; ++mb) {
            short8 a = *(const short8*)&shA[(mb * 16 + nl) * ASTRIDE + ks1 * 32 + q * 8];
            #pragma unroll
            for (int nb2 = 0; nb2 < 2; ++nb2)
                acc[mb][nb2] = __builtin_amdgcn_mfma_f32_16x16x32_bf16(
                    a, __builtin_bit_cast(short8, bFb[nb2]), acc[mb][nb2], 0, 0, 0);
        }
    }

    // ---- epilogue: d-partial s(t) = sum_{d in half} tanh(P + b1)*w2 ----
    // d = (nh*2 + nb2)*16 + nl, t = mb*16 + q*4 + r
    float b1v[2], w2v[2];
    #pragma unroll
    for (int nb2 = 0; nb2 < 2; ++nb2) {
        int d = (nh * 2 + nb2) * 16 + nl;
        b1v[nb2] = b1[h * HD_ + d];
        w2v[nb2] = w2[h * HD_ + d];
    }
    #pragma unroll
    for (int mb = 0; mb < 4; ++mb) {
        float p[4];
        #pragma unroll
        for (int r = 0; r < 4; ++r) {
            float s = 0.f;
            #pragma unroll
            for (int nb2 = 0; nb2 < 2; ++nb2)
                s += fast_tanh(acc[mb][nb2][r] + b1v[nb2]) * w2v[nb2];
            p[r] = s;
        }
        #pragma unroll
        for (int m = 1; m < 16; m <<= 1)
            #pragma unroll
            for (int r = 0; r < 4; ++r)
                p[r] += __shfl_xor(p[r], m, 64);
        if (nl == 0) {
            #pragma unroll
            for (int r = 0; r < 4; ++r)
                sS[(nh * 4 + h) * 64 + mb * 16 + q * 4 + r] = p[r];
        }
    }
    __syncthreads();   // sibling waves' d-halves both written

    // ---- phase 2: per-head local softmax partials (first 4 waves; w = head) ----
    if (tid < 256) {
        const int w = tid >> 6;
        float s = sS[w * 64 + lane] + sS[(4 + w) * 64 + lane];   // sum the two d-halves
        float m = s;
        #pragma unroll
        for (int off = 1; off < 64; off <<= 1)
            m = fmaxf(m, __shfl_xor(m, off, 64));
        float e = __expf(s - m);
        float Ss = e;
        #pragma unroll
        for (int off = 1; off < 64; off <<= 1)
            Ss += __shfl_xor(Ss, off, 64);
        sP4[lane * 4 + w] = e;                     // [t][h] for vectorized phase-3 read
        rawscore[((long)(b * H_ + w)) * T_ + tbase + lane] = s;
        if (lane == 0) {
            mS[((long)blockIdx.x * H_ + w) * 2 + 0] = m;
            mS[((long)blockIdx.x * H_ + w) * 2 + 1] = Ss;
        }
    }
    __syncthreads();

    // ---- phase 3: partial contexts; thread-half th covers heads {2th, 2th+1} ----
    {
        const int c  = tid & 255;
        const int th = tid >> 8;                   // 0 or 1 (uniform per wave)
        float c0 = 0.f, c1 = 0.f;
        const float* xr = x + (long)rowbase * C_ + c;
        const float2* pv2 = (const float2*)sP4;    // pv2[t*2+th] = {p[t][2th], p[t][2th+1]}
        #pragma unroll 8
        for (int t = 0; t < 64; ++t) {
            float xv = xr[(long)t * C_];           // L1/L2-hot (just staged)
            float2 pv = pv2[t * 2 + th];           // broadcast ds_read_b64
            c0 += pv.x * xv;
            c1 += pv.y * xv;
        }
        float* o = ctxp + (long)blockIdx.x * (H_ * C_) + th * 512 + c;
        o[0]   = c0;
        o[256] = c1;
    }
}

// ---------------- K2: combine partials -> weights (in-place over raw scores) + multi ----------------
__global__ void k2_combine(const float* __restrict__ ctxp, const float* __restrict__ mS,
                           float* __restrict__ weights, float* __restrict__ multi) {
    __shared__ float sm[64], sSl[64], sc[64];
    int bh = blockIdx.x;              // b*H + h
    int b = bh >> 2, h = bh & 3;
    int tid = threadIdx.x;
    if (tid < 64) {
        long blk = (long)b * 64 + tid;
        sm[tid]  = mS[(blk * H_ + h) * 2 + 0];
        sSl[tid] = mS[(blk * H_ + h) * 2 + 1];
    }
    __syncthreads();
    float m = -INFINITY;
    #pragma unroll 8
    for (int j = 0; j < 64; ++j) m = fmaxf(m, sm[j]);
    if (tid < 64) sc[tid] = __expf(sm[tid] - m);
    __syncthreads();
    float S = 0.f;
    #pragma unroll 8
    for (int j = 0; j < 64; ++j) S += sSl[j] * sc[j];
    float invS = 1.0f / S;

    float acc = 0.f;
    #pragma unroll 4
    for (int j = 0; j < 64; ++j)
        acc += ctxp[((long)(b * 64 + j) * H_ + h) * C_ + tid] * sc[j];
    multi[(long)b * (H_ * C_) + h * C_ + tid] = acc * invS;

    float* wr = weights + (long)bh * T_;
    #pragma unroll
    for (int i = 0; i < 16; ++i) {
        int t = tid + i * 256;
        float sv = wr[t];                 // raw score written by k1_fused
        wr[t] = __expf(sv - m) * invS;
    }
}

// ---------------- K4: Wo projection + bias + LayerNorm ----------------
__global__ void k4_out(const float* __restrict__ multiG, const float* __restrict__ Wo,
                       const float* __restrict__ bo, const float* __restrict__ gamma,
                       const float* __restrict__ beta, float* __restrict__ out) {
    __shared__ float multi[1024];
    __shared__ float red[256];
    int b = blockIdx.x, tid = threadIdx.x;
    {
        const float4* src = (const float4*)(multiG + (long)b * 1024);
        float4* dst = (float4*)multi;
        dst[tid] = src[tid];   // 256 float4 = 1024 floats
    }
    __syncthreads();
    float a0 = 0.f, a1 = 0.f, a2 = 0.f, a3 = 0.f;
    const float4* wrow = (const float4*)(Wo + (long)tid * 1024);
    const float4* mv = (const float4*)multi;
    #pragma unroll 8
    for (int j4 = 0; j4 < 256; j4 += 4) {
        float4 w0 = wrow[j4],     m0 = mv[j4];
        float4 w1 = wrow[j4 + 1], m1 = mv[j4 + 1];
        float4 w2 = wrow[j4 + 2], m2 = mv[j4 + 2];
        float4 w3 = wrow[j4 + 3], m3 = mv[j4 + 3];
        a0 += m0.x * w0.x + m0.y * w0.y + m0.z * w0.z + m0.w * w0.w;
        a1 += m1.x * w1.x + m1.y * w1.y + m1.z * w1.z + m1.w * w1.w;
        a2 += m2.x * w2.x + m2.y * w2.y + m2.z * w2.z + m2.w * w2.w;
        a3 += m3.x * w3.x + m3.y * w3.y + m3.z * w3.z + m3.w * w3.w;
    }
    float acc = bo[tid] + ((a0 + a1) + (a2 + a3));
    red[tid] = acc; __syncthreads();
    for (int st = 128; st > 0; st >>= 1) {
        if (tid < st) red[tid] += red[tid + st];
        __syncthreads();
    }
    float mu = red[0] * (1.0f / 256.0f); __syncthreads();
    float dv = acc - mu;
    red[tid] = dv * dv; __syncthreads();
    for (int st = 128; st > 0; st >>= 1) {
        if (tid < st) red[tid] += red[tid + st];
        __syncthreads();
    }
    float var = red[0] * (1.0f / 256.0f);
    out[(long)b * C_ + tid] = dv * rsqrtf(var + EPS_) * gamma[tid] + beta[tid];
}

extern "C" void kernel_launch(void* const* d_in, const int* in_sizes, int n_in,
                              void* d_out, int out_size, void* d_ws, size_t ws_size,
                              hipStream_t stream) {
    const float* x     = (const float*)d_in[0];
    const float* W1    = (const float*)d_in[1];
    const float* b1    = (const float*)d_in[2];
    const float* w2    = (const float*)d_in[3];
    const float* Wo    = (const float*)d_in[4];
    const float* bo    = (const float*)d_in[5];
    const float* gamma = (const float*)d_in[6];
    const float* beta  = (const float*)d_in[7];

    float* out     = (float*)d_out;          // (B,C) = 16384 floats
    float* weights = out + B_ * C_;          // (B,H,T) = 1048576 floats (holds raw scores first)

    // workspace: ctxp 4096*4*256 fp32 (16 MiB) + mS 4096*4*2 + multi 64*1024 + w1f (128 KiB)
    float* ctxp  = (float*)d_ws;
    float* mS    = ctxp + (long)4096 * H_ * C_;
    float* multi = mS + (long)4096 * H_ * 2;
    uint4* w1f   = (uint4*)(multi + B_ * H_ * C_);

    k0_w1frag <<<32, 256, 0, stream>>>(W1, w1f);
    k1_fused  <<<4096, 512, 0, stream>>>(x, w1f, b1, w2, weights, ctxp, mS);
    k2_combine<<<256, 256, 0, stream>>>(ctxp, mS, weights, multi);
    k4_out    <<<64, 256, 0, stream>>>(multi, Wo, bo, gamma, beta, out);
}

// Round 5
// 475.565 us; speedup vs baseline: 1.0065x; 1.0065x over previous
//
#include <hip/hip_runtime.h>
#include <hip/hip_bf16.h>
#include <math.h>

#define B_ 64
#define T_ 4096
#define C_ 256
#define H_ 4
#define HD_ 64
#define EPS_ 1e-5f

// k1 tile: 32 rows per block, 128 blocks per batch
#define TILE_ 32
#define NBLK_ 128   // T_/TILE_

typedef __attribute__((ext_vector_type(4))) float floatx4;
typedef __attribute__((ext_vector_type(8))) short short8;   // 8 bf16 = 4 VGPRs (MFMA A/B frag)

#if __has_builtin(__builtin_amdgcn_cvt_pk_bf16_f32)
typedef __attribute__((ext_vector_type(2))) __bf16 bf16x2_t;
__device__ __forceinline__ unsigned int pack_bf16x2(float a, float b) {
    bf16x2_t v = __builtin_amdgcn_cvt_pk_bf16_f32(a, b);
    return __builtin_bit_cast(unsigned int, v);
}
#else
__device__ __forceinline__ unsigned int pack_bf16x2(float a, float b) {
    unsigned int ua = __builtin_bit_cast(unsigned int, a);
    unsigned int ub = __builtin_bit_cast(unsigned int, b);
    ua = (ua + 0x7fffu + ((ua >> 16) & 1u)) >> 16;   // RNE
    ub = (ub + 0x7fffu + ((ub >> 16) & 1u)) >> 16;
    return ua | (ub << 16);
}
#endif

// tanh(x) = 1 - 2/(e^{2x}+1) = 1 - 2*rcp(exp2(x*2log2e)+1)
// 5 ops (mul, exp2, add, rcp, fma); exact at +/-inf; error ~1e-7.
__device__ __forceinline__ float fast_tanh(float v) {
    float t = v * 2.8853900817779268f;          // 2*log2(e)
#if __has_builtin(__builtin_amdgcn_exp2f)
    float e2 = __builtin_amdgcn_exp2f(t);
#else
    float e2 = exp2f(t);
#endif
#if __has_builtin(__builtin_amdgcn_rcpf)
    return fmaf(-2.0f, __builtin_amdgcn_rcpf(e2 + 1.0f), 1.0f);
#else
    return 1.0f - 2.0f / (e2 + 1.0f);
#endif
}

// ---------------- K0: W1 (H,C,HD) fp32 -> fragment-major bf16 B-operand ----------------
// w1f[((h*8 + ks)*4 + nb)*64 + lane] = uint4 holding 8 bf16:
//   B[nb*16 + nl][ks*32 + q*8 + j], j=0..7   (nl = lane&15, q = lane>>4)
__global__ void k0_w1frag(const float* __restrict__ W1, uint4* __restrict__ w1f) {
    int h  = blockIdx.x >> 3;       // grid 32 = H*8
    int ks = blockIdx.x & 7;
    int nb = threadIdx.x >> 6;      // 4 waves = 4 n-tiles
    int l  = threadIdx.x & 63;
    int nl = l & 15, q = l >> 4;
    int d  = nb * 16 + nl;
    const float* src = W1 + ((long)h * C_ + ks * 32 + q * 8) * HD_ + d;
    float v[8];
    #pragma unroll
    for (int j = 0; j < 8; ++j) v[j] = src[j * HD_];
    uint4 ua;
    ua.x = pack_bf16x2(v[0], v[1]); ua.y = pack_bf16x2(v[2], v[3]);
    ua.z = pack_bf16x2(v[4], v[5]); ua.w = pack_bf16x2(v[6], v[7]);
    w1f[((long)blockIdx.x * 4 + nb) * 64 + l] = ua;
}

// ---------------- K1 fused: scores (MFMA) + partial softmax + partial context ----------------
// grid 8192 (32 rows each), block 256 = 4 waves, wave w = head w.
// Half-size tile vs prior rounds: 2x blocks at independent phases per CU
// (5 resident) de-convoys HBM demand; 32KB x-tile is L1-resident for phase 3.
#define ASTRIDE 264   // bf16 elements per row (256 + 8 pad)
__global__ __launch_bounds__(256, 5)   // 5 blocks/CU (20 waves), VGPR cap 102
void k1_fused(const float* __restrict__ x, const uint4* __restrict__ w1f,
              const float* __restrict__ b1, const float* __restrict__ w2,
              float* __restrict__ rawscore, float* __restrict__ ctxp,
              float* __restrict__ mS) {
    __shared__ __align__(16) unsigned short shA[TILE_ * ASTRIDE];  // 16.5 KiB
    __shared__ float sS[4 * TILE_];                // raw scores per head
    __shared__ __align__(16) float sP4[TILE_ * 4]; // exp(s - m_loc), layout [t][h]

    const int tid  = threadIdx.x;
    const int lane = tid & 63;
    const int w    = tid >> 6;        // wave id == head id
    const int nl   = lane & 15;
    const int q    = lane >> 4;
    const int rowbase = blockIdx.x * TILE_;        // row = b*T + t
    const int b       = blockIdx.x >> 7;           // 128 blocks per batch
    const int tbase   = (blockIdx.x & 127) * TILE_;

    // ---- stage A tile, lane-major (perfectly coalesced 1KiB/wave loads) ----
    // wave w covers rows w*8 .. w*8+7; lane l covers cols 4l..4l+3 of each row.
    {
        const int r0 = w * 8;
        const float* xp = x + (long)(rowbase + r0) * C_ + lane * 4;
        #pragma unroll
        for (int i = 0; i < 8; ++i) {
            float4 f = *(const float4*)(xp + (long)i * C_);
            uint2 u;
            u.x = pack_bf16x2(f.x, f.y);
            u.y = pack_bf16x2(f.z, f.w);
            *(uint2*)&shA[(r0 + i) * ASTRIDE + lane * 4] = u;
        }
    }

    floatx4 acc[2][4];
    #pragma unroll
    for (int i = 0; i < 2; ++i)
        #pragma unroll
        for (int j = 0; j < 4; ++j)
            acc[i][j] = (floatx4){0.f, 0.f, 0.f, 0.f};

    // per-head fragment base
    const uint4* bW = w1f + (long)w * (8 * 4 * 64) + lane;

    // prefetch ks=0 B-fragments BEFORE the barrier (independent of LDS)
    uint4 bFa[4], bFb[4];
    #pragma unroll
    for (int nb = 0; nb < 4; ++nb) bFa[nb] = bW[nb * 64];

    __syncthreads();   // the ONLY K-side barrier

    // ---- K-loop: 8 steps x 8 MFMA, depth-1 B prefetch, all indices static ----
    #pragma unroll
    for (int kp = 0; kp < 4; ++kp) {
        const int ks0 = 2 * kp, ks1 = 2 * kp + 1;
        #pragma unroll
        for (int nb = 0; nb < 4; ++nb) bFb[nb] = bW[(ks1 * 4 + nb) * 64];
        #pragma unroll
        for (int mb = 0; mb < 2; ++mb) {
            short8 a = *(const short8*)&shA[(mb * 16 + nl) * ASTRIDE + ks0 * 32 + q * 8];
            #pragma unroll
            for (int nb = 0; nb < 4; ++nb)
                acc[mb][nb] = __builtin_amdgcn_mfma_f32_16x16x32_bf16(
                    a, __builtin_bit_cast(short8, bFa[nb]), acc[mb][nb], 0, 0, 0);
        }
        if (kp < 3) {
            #pragma unroll
            for (int nb = 0; nb < 4; ++nb) bFa[nb] = bW[((ks0 + 2) * 4 + nb) * 64];
        }
        #pragma unroll
        for (int mb = 0; mb < 2; ++mb) {
            short8 a = *(const short8*)&shA[(mb * 16 + nl) * ASTRIDE + ks1 * 32 + q * 8];
            #pragma unroll
            for (int nb = 0; nb < 4; ++nb)
                acc[mb][nb] = __builtin_amdgcn_mfma_f32_16x16x32_bf16(
                    a, __builtin_bit_cast(short8, bFb[nb]), acc[mb][nb], 0, 0, 0);
        }
    }

    // ---- epilogue: s(t) = sum_d tanh(P + b1)*w2  (d = nb*16 + nl, t = mb*16 + q*4 + r) ----
    float b1v[4], w2v[4];
    #pragma unroll
    for (int nb = 0; nb < 4; ++nb) {
        int d = nb * 16 + nl;
        b1v[nb] = b1[w * HD_ + d];
        w2v[nb] = w2[w * HD_ + d];
    }
    #pragma unroll
    for (int mb = 0; mb < 2; ++mb) {
        float p[4];
        #pragma unroll
        for (int r = 0; r < 4; ++r) {
            float s = 0.f;
            #pragma unroll
            for (int nb = 0; nb < 4; ++nb)
                s += fast_tanh(acc[mb][nb][r] + b1v[nb]) * w2v[nb];
            p[r] = s;
        }
        #pragma unroll
        for (int m = 1; m < 16; m <<= 1)
            #pragma unroll
            for (int r = 0; r < 4; ++r)
                p[r] += __shfl_xor(p[r], m, 64);
        if (nl == 0) {
            #pragma unroll
            for (int r = 0; r < 4; ++r)
                sS[w * TILE_ + mb * 16 + q * 4 + r] = p[r];
        }
    }
    __syncthreads();

    // ---- phase 2: per-head local softmax partials over this block's 32 t values ----
    if (tid < 128) {
        const int wh = tid >> 5;       // head
        const int tl = tid & 31;       // t within tile
        float s = sS[wh * TILE_ + tl];
        float m = s;
        #pragma unroll
        for (int off = 1; off < 32; off <<= 1)
            m = fmaxf(m, __shfl_xor(m, off, 32));
        float e = __expf(s - m);
        float Ss = e;
        #pragma unroll
        for (int off = 1; off < 32; off <<= 1)
            Ss += __shfl_xor(Ss, off, 32);
        sP4[tl * 4 + wh] = e;                      // [t][h] for vectorized phase-3 read
        rawscore[((long)(b * H_ + wh)) * T_ + tbase + tl] = s;
        if (tl == 0) {
            mS[((long)blockIdx.x * H_ + wh) * 2 + 0] = m;
            mS[((long)blockIdx.x * H_ + wh) * 2 + 1] = Ss;
        }
    }
    __syncthreads();

    // ---- phase 3: partial contexts ctx_loc[h][c] = sum_t p[t][h] * x[t][c] (x L1-resident) ----
    {
        float c0 = 0.f, c1 = 0.f, c2 = 0.f, c3 = 0.f;
        const float* xr = x + (long)rowbase * C_ + tid;
        const float4* pv4 = (const float4*)sP4;
        #pragma unroll 8
        for (int t = 0; t < TILE_; ++t) {
            float xv = xr[(long)t * C_];
            float4 pv = pv4[t];                    // one broadcast ds_read_b128
            c0 += pv.x * xv;
            c1 += pv.y * xv;
            c2 += pv.z * xv;
            c3 += pv.w * xv;
        }
        float* o = ctxp + (long)blockIdx.x * (H_ * C_) + tid;
        o[0]   = c0;
        o[256] = c1;
        o[512] = c2;
        o[768] = c3;
    }
}

// ---------------- K2: combine partials -> weights (in-place over raw scores) + multi ----------------
__global__ void k2_combine(const float* __restrict__ ctxp, const float* __restrict__ mS,
                           float* __restrict__ weights, float* __restrict__ multi) {
    __shared__ float sm[NBLK_], sSl[NBLK_], sc[NBLK_];
    int bh = blockIdx.x;              // b*H + h
    int b = bh >> 2, h = bh & 3;
    int tid = threadIdx.x;
    if (tid < NBLK_) {
        long blk = (long)b * NBLK_ + tid;
        sm[tid]  = mS[(blk * H_ + h) * 2 + 0];
        sSl[tid] = mS[(blk * H_ + h) * 2 + 1];
    }
    __syncthreads();
    float m = -INFINITY;
    #pragma unroll 8
    for (int j = 0; j < NBLK_; ++j) m = fmaxf(m, sm[j]);
    if (tid < NBLK_) sc[tid] = __expf(sm[tid] - m);
    __syncthreads();
    float S = 0.f;
    #pragma unroll 8
    for (int j = 0; j < NBLK_; ++j) S += sSl[j] * sc[j];
    float invS = 1.0f / S;

    float acc = 0.f;
    #pragma unroll 4
    for (int j = 0; j < NBLK_; ++j)
        acc += ctxp[((long)(b * NBLK_ + j) * H_ + h) * C_ + tid] * sc[j];
    multi[(long)b * (H_ * C_) + h * C_ + tid] = acc * invS;

    float* wr = weights + (long)bh * T_;
    #pragma unroll
    for (int i = 0; i < 16; ++i) {
        int t = tid + i * 256;
        float sv = wr[t];                 // raw score written by k1_fused
        wr[t] = __expf(sv - m) * invS;
    }
}

// ---------------- K4: Wo projection + bias + LayerNorm ----------------
__global__ void k4_out(const float* __restrict__ multiG, const float* __restrict__ Wo,
                       const float* __restrict__ bo, const float* __restrict__ gamma,
                       const float* __restrict__ beta, float* __restrict__ out) {
    __shared__ float multi[1024];
    __shared__ float red[256];
    int b = blockIdx.x, tid = threadIdx.x;
    {
        const float4* src = (const float4*)(multiG + (long)b * 1024);
        float4* dst = (float4*)multi;
        dst[tid] = src[tid];   // 256 float4 = 1024 floats
    }
    __syncthreads();
    float a0 = 0.f, a1 = 0.f, a2 = 0.f, a3 = 0.f;
    const float4* wrow = (const float4*)(Wo + (long)tid * 1024);
    const float4* mv = (const float4*)multi;
    #pragma unroll 8
    for (int j4 = 0; j4 < 256; j4 += 4) {
        float4 w0 = wrow[j4],     m0 = mv[j4];
        float4 w1 = wrow[j4 + 1], m1 = mv[j4 + 1];
        float4 w2 = wrow[j4 + 2], m2 = mv[j4 + 2];
        float4 w3 = wrow[j4 + 3], m3 = mv[j4 + 3];
        a0 += m0.x * w0.x + m0.y * w0.y + m0.z * w0.z + m0.w * w0.w;
        a1 += m1.x * w1.x + m1.y * w1.y + m1.z * w1.z + m1.w * w1.w;
        a2 += m2.x * w2.x + m2.y * w2.y + m2.z * w2.z + m2.w * w2.w;
        a3 += m3.x * w3.x + m3.y * w3.y + m3.z * w3.z + m3.w * w3.w;
    }
    float acc = bo[tid] + ((a0 + a1) + (a2 + a3));
    red[tid] = acc; __syncthreads();
    for (int st = 128; st > 0; st >>= 1) {
        if (tid < st) red[tid] += red[tid + st];
        __syncthreads();
    }
    float mu = red[0] * (1.0f / 256.0f); __syncthreads();
    float dv = acc - mu;
    red[tid] = dv * dv; __syncthreads();
    for (int st = 128; st > 0; st >>= 1) {
        if (tid < st) red[tid] += red[tid + st];
        __syncthreads();
    }
    float var = red[0] * (1.0f / 256.0f);
    out[(long)b * C_ + tid] = dv * rsqrtf(var + EPS_) * gamma[tid] + beta[tid];
}

extern "C" void kernel_launch(void* const* d_in, const int* in_sizes, int n_in,
                              void* d_out, int out_size, void* d_ws, size_t ws_size,
                              hipStream_t stream) {
    const float* x     = (const float*)d_in[0];
    const float* W1    = (const float*)d_in[1];
    const float* b1    = (const float*)d_in[2];
    const float* w2    = (const float*)d_in[3];
    const float* Wo    = (const float*)d_in[4];
    const float* bo    = (const float*)d_in[5];
    const float* gamma = (const float*)d_in[6];
    const float* beta  = (const float*)d_in[7];

    float* out     = (float*)d_out;          // (B,C) = 16384 floats
    float* weights = out + B_ * C_;          // (B,H,T) = 1048576 floats (holds raw scores first)

    // workspace: ctxp 8192*1024 fp32 (32 MiB) + mS 8192*4*2 + multi 64*1024 + w1f (128 KiB)
    const long NB = (long)B_ * NBLK_;        // 8192 k1 blocks
    float* ctxp  = (float*)d_ws;
    float* mS    = ctxp + NB * (H_ * C_);
    float* multi = mS + NB * H_ * 2;
    uint4* w1f   = (uint4*)(multi + B_ * H_ * C_);

    k0_w1frag <<<32, 256, 0, stream>>>(W1, w1f);
    k1_fused  <<<NB, 256, 0, stream>>>(x, w1f, b1, w2, weights, ctxp, mS);
    k2_combine<<<256, 256, 0, stream>>>(ctxp, mS, weights, multi);
    k4_out    <<<64, 256, 0, stream>>>(multi, Wo, bo, gamma, beta, out);
}

// Round 6
// 423.494 us; speedup vs baseline: 1.1302x; 1.1230x over previous
//
#include <hip/hip_runtime.h>
#include <hip/hip_bf16.h>
#include <math.h>

#define B_ 64
#define T_ 4096
#define C_ 256
#define H_ 4
#define HD_ 64
#define EPS_ 1e-5f

#define TILE_ 64
#define NBLK_ 64    // T_/TILE_

typedef __attribute__((ext_vector_type(4))) float floatx4;
typedef __attribute__((ext_vector_type(8))) short short8;   // 8 bf16 = 4 VGPRs (MFMA A/B frag)

#if __has_builtin(__builtin_amdgcn_cvt_pk_bf16_f32)
typedef __attribute__((ext_vector_type(2))) __bf16 bf16x2_t;
__device__ __forceinline__ unsigned int pack_bf16x2(float a, float b) {
    bf16x2_t v = __builtin_amdgcn_cvt_pk_bf16_f32(a, b);
    return __builtin_bit_cast(unsigned int, v);
}
#else
__device__ __forceinline__ unsigned int pack_bf16x2(float a, float b) {
    unsigned int ua = __builtin_bit_cast(unsigned int, a);
    unsigned int ub = __builtin_bit_cast(unsigned int, b);
    ua = (ua + 0x7fffu + ((ua >> 16) & 1u)) >> 16;   // RNE
    ub = (ub + 0x7fffu + ((ub >> 16) & 1u)) >> 16;
    return ua | (ub << 16);
}
#endif

// tanh(x) = 1 - 2/(e^{2x}+1) = 1 - 2*rcp(exp2(x*2log2e)+1); ~5 ops, err ~1e-7.
__device__ __forceinline__ float fast_tanh(float v) {
    float t = v * 2.8853900817779268f;          // 2*log2(e)
#if __has_builtin(__builtin_amdgcn_exp2f)
    float e2 = __builtin_amdgcn_exp2f(t);
#else
    float e2 = exp2f(t);
#endif
#if __has_builtin(__builtin_amdgcn_rcpf)
    return fmaf(-2.0f, __builtin_amdgcn_rcpf(e2 + 1.0f), 1.0f);
#else
    return 1.0f - 2.0f / (e2 + 1.0f);
#endif
}

// ---------------- K0: W1 (H,C,HD) fp32 -> fragment-major bf16 B-operand ----------------
// w1f[((h*8 + ks)*4 + nb)*64 + lane] = uint4 holding 8 bf16:
//   B[nb*16 + nl][ks*32 + q*8 + j], j=0..7   (nl = lane&15, q = lane>>4)
__global__ void k0_w1frag(const float* __restrict__ W1, uint4* __restrict__ w1f) {
    int h  = blockIdx.x >> 3;       // grid 32 = H*8
    int ks = blockIdx.x & 7;
    int nb = threadIdx.x >> 6;      // 4 waves = 4 n-tiles
    int l  = threadIdx.x & 63;
    int nl = l & 15, q = l >> 4;
    int d  = nb * 16 + nl;
    const float* src = W1 + ((long)h * C_ + ks * 32 + q * 8) * HD_ + d;
    float v[8];
    #pragma unroll
    for (int j = 0; j < 8; ++j) v[j] = src[j * HD_];
    uint4 ua;
    ua.x = pack_bf16x2(v[0], v[1]); ua.y = pack_bf16x2(v[2], v[3]);
    ua.z = pack_bf16x2(v[4], v[5]); ua.w = pack_bf16x2(v[6], v[7]);
    w1f[((long)blockIdx.x * 4 + nb) * 64 + l] = ua;
}

// ---------------- K1 fused (R2 structure, best measured): scores + partial softmax + ctx ----------------
// grid 4096 (64 rows each), block 256 = 4 waves, wave w = head w.
#define ASTRIDE 264   // bf16 elements per row (256 + 8 pad)
__global__ __launch_bounds__(256, 4)
void k1_fused(const float* __restrict__ x, const uint4* __restrict__ w1f,
              const float* __restrict__ b1, const float* __restrict__ w2,
              float* __restrict__ rawscore, float* __restrict__ ctxp,
              float* __restrict__ mS) {
    __shared__ __align__(16) unsigned short shA[TILE_ * ASTRIDE];  // 33 KiB
    __shared__ float sS[4 * TILE_];
    __shared__ __align__(16) float sP4[TILE_ * 4];

    const int tid  = threadIdx.x;
    const int lane = tid & 63;
    const int w    = tid >> 6;        // wave id == head id
    const int nl   = lane & 15;
    const int q    = lane >> 4;
    const int rowbase = blockIdx.x * TILE_;
    const int b       = blockIdx.x >> 6;
    const int tbase   = (blockIdx.x & 63) * TILE_;

    // ---- stage full A tile ----
    const int arow = tid >> 2;          // 0..63
    const int acol = (tid & 3) * 8;     // 0,8,16,24 within each 32-chunk
    const float* aptr = x + (long)(rowbase + arow) * C_ + acol;
    #pragma unroll
    for (int kc = 0; kc < 8; ++kc) {
        const float4* ap = (const float4*)(aptr + kc * 32);
        float4 f0 = ap[0], f1 = ap[1];
        uint4 ua;
        ua.x = pack_bf16x2(f0.x, f0.y); ua.y = pack_bf16x2(f0.z, f0.w);
        ua.z = pack_bf16x2(f1.x, f1.y); ua.w = pack_bf16x2(f1.z, f1.w);
        *(uint4*)&shA[arow * ASTRIDE + kc * 32 + acol] = ua;
    }

    floatx4 acc[4][4];
    #pragma unroll
    for (int i = 0; i < 4; ++i)
        #pragma unroll
        for (int j = 0; j < 4; ++j)
            acc[i][j] = (floatx4){0.f, 0.f, 0.f, 0.f};

    const uint4* bW = w1f + (long)w * (8 * 4 * 64) + lane;

    uint4 bFa[4], bFb[4];
    #pragma unroll
    for (int nb = 0; nb < 4; ++nb) bFa[nb] = bW[nb * 64];

    __syncthreads();   // the ONLY K-side barrier

    #pragma unroll
    for (int kp = 0; kp < 4; ++kp) {
        const int ks0 = 2 * kp, ks1 = 2 * kp + 1;
        #pragma unroll
        for (int nb = 0; nb < 4; ++nb) bFb[nb] = bW[(ks1 * 4 + nb) * 64];
        #pragma unroll
        for (int mb = 0; mb < 4; ++mb) {
            short8 a = *(const short8*)&shA[(mb * 16 + nl) * ASTRIDE + ks0 * 32 + q * 8];
            #pragma unroll
            for (int nb = 0; nb < 4; ++nb)
                acc[mb][nb] = __builtin_amdgcn_mfma_f32_16x16x32_bf16(
                    a, __builtin_bit_cast(short8, bFa[nb]), acc[mb][nb], 0, 0, 0);
        }
        if (kp < 3) {
            #pragma unroll
            for (int nb = 0; nb < 4; ++nb) bFa[nb] = bW[((ks0 + 2) * 4 + nb) * 64];
        }
        #pragma unroll
        for (int mb = 0; mb < 4; ++mb) {
            short8 a = *(const short8*)&shA[(mb * 16 + nl) * ASTRIDE + ks1 * 32 + q * 8];
            #pragma unroll
            for (int nb = 0; nb < 4; ++nb)
                acc[mb][nb] = __builtin_amdgcn_mfma_f32_16x16x32_bf16(
                    a, __builtin_bit_cast(short8, bFb[nb]), acc[mb][nb], 0, 0, 0);
        }
    }

    // ---- epilogue: s(t) = sum_d tanh(P + b1)*w2 ----
    float b1v[4], w2v[4];
    #pragma unroll
    for (int nb = 0; nb < 4; ++nb) {
        int d = nb * 16 + nl;
        b1v[nb] = b1[w * HD_ + d];
        w2v[nb] = w2[w * HD_ + d];
    }
    #pragma unroll
    for (int mb = 0; mb < 4; ++mb) {
        float p[4];
        #pragma unroll
        for (int r = 0; r < 4; ++r) {
            float s = 0.f;
            #pragma unroll
            for (int nb = 0; nb < 4; ++nb)
                s += fast_tanh(acc[mb][nb][r] + b1v[nb]) * w2v[nb];
            p[r] = s;
        }
        #pragma unroll
        for (int m = 1; m < 16; m <<= 1)
            #pragma unroll
            for (int r = 0; r < 4; ++r)
                p[r] += __shfl_xor(p[r], m, 64);
        if (nl == 0) {
            #pragma unroll
            for (int r = 0; r < 4; ++r)
                sS[w * TILE_ + mb * 16 + q * 4 + r] = p[r];
        }
    }

    // ---- phase 2: per-head local softmax partials over 64 t ----
    {
        float s = sS[w * TILE_ + lane];
        float m = s;
        #pragma unroll
        for (int off = 1; off < 64; off <<= 1)
            m = fmaxf(m, __shfl_xor(m, off, 64));
        float e = __expf(s - m);
        float Ss = e;
        #pragma unroll
        for (int off = 1; off < 64; off <<= 1)
            Ss += __shfl_xor(Ss, off, 64);
        sP4[lane * 4 + w] = e;
        rawscore[((long)(b * H_ + w)) * T_ + tbase + lane] = s;
        if (lane == 0) {
            mS[((long)blockIdx.x * H_ + w) * 2 + 0] = m;
            mS[((long)blockIdx.x * H_ + w) * 2 + 1] = Ss;
        }
    }
    __syncthreads();

    // ---- phase 3: partial contexts (x re-read, cache-hot) ----
    {
        float c0 = 0.f, c1 = 0.f, c2 = 0.f, c3 = 0.f;
        const float* xr = x + (long)rowbase * C_ + tid;
        const float4* pv4 = (const float4*)sP4;
        #pragma unroll 8
        for (int t = 0; t < TILE_; ++t) {
            float xv = xr[(long)t * C_];
            float4 pv = pv4[t];
            c0 += pv.x * xv;
            c1 += pv.y * xv;
            c2 += pv.z * xv;
            c3 += pv.w * xv;
        }
        float* o = ctxp + (long)blockIdx.x * (H_ * C_) + tid;
        o[0]   = c0;
        o[256] = c1;
        o[512] = c2;
        o[768] = c3;
    }
}

// ---------------- K2: combine partials -> multi + per-(b,h) {m, invS} ----------------
// grid 256 = (b,h); 1024 threads: c = tid&255, js = tid>>2... js = tid>>8 in [0,4).
// j-loop split 4-way with LDS reduction: 4x the load parallelism of the old version.
__global__ __launch_bounds__(1024)
void k2_combine(const float* __restrict__ ctxp, const float* __restrict__ mS,
                float* __restrict__ gms, float* __restrict__ multi) {
    __shared__ float sm[NBLK_], sSl[NBLK_];
    __shared__ float red[4][256];
    int bh = blockIdx.x;              // b*H + h
    int b = bh >> 2, h = bh & 3;
    int tid = threadIdx.x;
    int c  = tid & 255;
    int js = tid >> 8;                // 0..3
    if (tid < NBLK_) {
        long blk = (long)b * NBLK_ + tid;
        sm[tid]  = mS[(blk * H_ + h) * 2 + 0];
        sSl[tid] = mS[(blk * H_ + h) * 2 + 1];
    }
    __syncthreads();
    float m = -INFINITY;
    #pragma unroll 8
    for (int j = 0; j < NBLK_; ++j) m = fmaxf(m, sm[j]);
    float S = 0.f;
    #pragma unroll 8
    for (int j = 0; j < NBLK_; ++j) S += sSl[j] * __expf(sm[j] - m);
    float invS = 1.0f / S;
    if (tid == 0) { gms[bh * 2 + 0] = m; gms[bh * 2 + 1] = invS; }

    float acc = 0.f;
    #pragma unroll
    for (int jj = 0; jj < NBLK_ / 4; ++jj) {
        int j = js * (NBLK_ / 4) + jj;
        acc += ctxp[((long)(b * NBLK_ + j) * H_ + h) * C_ + c] * __expf(sm[j] - m);
    }
    red[js][c] = acc;
    __syncthreads();
    if (js == 0)
        multi[(long)b * (H_ * C_) + h * C_ + c] =
            (red[0][c] + red[1][c] + red[2][c] + red[3][c]) * invS;
}

// ---------------- K3: weights = exp(raw - m) * invS (fully parallel rewrite) ----------------
// grid 512: 2 blocks per (b,h), 256 threads, 2 float4 each (2048 floats/block).
__global__ void k3_weights(const float* __restrict__ gms, float* __restrict__ weights) {
    int bh = blockIdx.x >> 1, half = blockIdx.x & 1;
    float m = gms[bh * 2 + 0], invS = gms[bh * 2 + 1];
    float4* wr = (float4*)(weights + (long)bh * T_ + half * 2048);
    int tid = threadIdx.x;
    #pragma unroll
    for (int i = 0; i < 2; ++i) {
        float4 v = wr[tid + i * 256];
        v.x = __expf(v.x - m) * invS;
        v.y = __expf(v.y - m) * invS;
        v.z = __expf(v.z - m) * invS;
        v.w = __expf(v.w - m) * invS;
        wr[tid + i * 256] = v;
    }
}

// ---------------- K4a: out_raw = multi @ Wo^T + bo (wave-cooperative dots) ----------------
// grid 1024 = b*16 + cs; 256 threads = 4 waves. Wave w computes c = cs*16 + w*4 + {0..3}.
// Lane-parallel over j: each lane loads float4 at j = k*256 + l*4 -> perfectly coalesced.
__global__ __launch_bounds__(256)
void k4a_proj(const float* __restrict__ multiG, const float* __restrict__ Wo,
              const float* __restrict__ bo, float* __restrict__ outraw) {
    __shared__ __align__(16) float multi[1024];
    int b = blockIdx.x >> 4, cs = blockIdx.x & 15;
    int tid = threadIdx.x, w = tid >> 6, l = tid & 63;
    ((float4*)multi)[tid] = ((const float4*)(multiG + (long)b * 1024))[tid];
    __syncthreads();
    float a[4];
    #pragma unroll
    for (int cc = 0; cc < 4; ++cc) {
        int c = cs * 16 + w * 4 + cc;
        const float4* wrow = (const float4*)(Wo + (long)c * 1024);
        const float4* mv = (const float4*)multi;
        float s = 0.f;
        #pragma unroll
        for (int k = 0; k < 4; ++k) {
            float4 wv = wrow[k * 64 + l];
            float4 m4 = mv[k * 64 + l];
            s += wv.x * m4.x + wv.y * m4.y + wv.z * m4.z + wv.w * m4.w;
        }
        a[cc] = s;
    }
    #pragma unroll
    for (int off = 1; off < 64; off <<= 1)
        #pragma unroll
        for (int cc = 0; cc < 4; ++cc)
            a[cc] += __shfl_xor(a[cc], off, 64);
    if (l == 0) {
        #pragma unroll
        for (int cc = 0; cc < 4; ++cc) {
            int c = cs * 16 + w * 4 + cc;
            outraw[(long)b * C_ + c] = a[cc] + bo[c];
        }
    }
}

// ---------------- K4b: LayerNorm over the 256 outputs per batch row ----------------
__global__ void k4b_ln(const float* __restrict__ outraw, const float* __restrict__ gamma,
                       const float* __restrict__ beta, float* __restrict__ out) {
    __shared__ float red[256];
    int b = blockIdx.x, tid = threadIdx.x;
    float acc = outraw[(long)b * C_ + tid];
    red[tid] = acc; __syncthreads();
    for (int st = 128; st > 0; st >>= 1) {
        if (tid < st) red[tid] += red[tid + st];
        __syncthreads();
    }
    float mu = red[0] * (1.0f / 256.0f); __syncthreads();
    float dv = acc - mu;
    red[tid] = dv * dv; __syncthreads();
    for (int st = 128; st > 0; st >>= 1) {
        if (tid < st) red[tid] += red[tid + st];
        __syncthreads();
    }
    float var = red[0] * (1.0f / 256.0f);
    out[(long)b * C_ + tid] = dv * rsqrtf(var + EPS_) * gamma[tid] + beta[tid];
}

extern "C" void kernel_launch(void* const* d_in, const int* in_sizes, int n_in,
                              void* d_out, int out_size, void* d_ws, size_t ws_size,
                              hipStream_t stream) {
    const float* x     = (const float*)d_in[0];
    const float* W1    = (const float*)d_in[1];
    const float* b1    = (const float*)d_in[2];
    const float* w2    = (const float*)d_in[3];
    const float* Wo    = (const float*)d_in[4];
    const float* bo    = (const float*)d_in[5];
    const float* gamma = (const float*)d_in[6];
    const float* beta  = (const float*)d_in[7];

    float* out     = (float*)d_out;          // (B,C) = 16384 floats
    float* weights = out + B_ * C_;          // (B,H,T) = 1048576 floats (raw scores first)

    // workspace layout
    const long NB = (long)B_ * NBLK_;        // 4096 k1 blocks
    float* ctxp   = (float*)d_ws;            // 4096*1024 = 16 MiB
    float* mS     = ctxp + NB * (H_ * C_);   // 4096*4*2
    float* multi  = mS + NB * H_ * 2;        // 64*1024
    uint4* w1f    = (uint4*)(multi + B_ * H_ * C_);   // 128 KiB
    float* gms    = (float*)w1f + 32768;     // 256*2
    float* outraw = gms + 512;               // 64*256

    k0_w1frag <<<32, 256, 0, stream>>>(W1, w1f);
    k1_fused  <<<NB, 256, 0, stream>>>(x, w1f, b1, w2, weights, ctxp, mS);
    k2_combine<<<256, 1024, 0, stream>>>(ctxp, mS, gms, multi);
    k3_weights<<<512, 256, 0, stream>>>(gms, weights);
    k4a_proj  <<<1024, 256, 0, stream>>>(multi, Wo, bo, outraw);
    k4b_ln    <<<64, 256, 0, stream>>>(outraw, gamma, beta, out);
}